// Round 15
// baseline (173.617 us; speedup 1.0000x reference)
//
#include <hip/hip_runtime.h>
#include <hip/hip_fp16.h>
#include <math.h>

#define N_NODES 50000
#define F_DIM   128
#define E_EDGES 800000
#define NPB     16      // nodes per gemm block -> 3125 blocks exactly
#define NBLK    3125
#define CAP     64      // bucket capacity per node
#define APAD_H  136     // padded row stride in halves (272 B)
#define NMASKW  400000  // 12.8M elements / 32 bits
#define FILL_BLOCKS (E_EDGES / 256)            // 3125
#define PACK_BLOCKS ((N_NODES * F_DIM) / 1024) // 6250
#define WPACK_BLOCKS 64                        // 2*128*64 half2 words / 256

typedef _Float16 h2v __attribute__((ext_vector_type(2)));

// fdot2: 2-way fp16 dot with f32 accumulate (falls back to cvt+fma if unavailable)
__device__ __forceinline__ float fd2(float a, float b, float c) {
#if __has_builtin(__builtin_amdgcn_fdot2)
  return __builtin_amdgcn_fdot2(__builtin_bit_cast(h2v, a),
                                __builtin_bit_cast(h2v, b), c, false);
#else
  float2 fa = __half22float2(__builtin_bit_cast(__half2, a));
  float2 fb = __half22float2(__builtin_bit_cast(__half2, b));
  return fmaf(fa.x, fb.x, fmaf(fa.y, fb.y, c));
#endif
}

// ---------------- JAX threefry (partitionable path, o0^o1) — verified r2 ----------------
__device__ __forceinline__ unsigned rotl32(unsigned x, int d) {
  return (x << d) | (x >> (32 - d));
}

__device__ __forceinline__ void tf2x32(unsigned k0, unsigned k1,
                                       unsigned c0, unsigned c1,
                                       unsigned &o0, unsigned &o1) {
  unsigned ks2 = k0 ^ k1 ^ 0x1BD11BDAu;
  unsigned x0 = c0 + k0, x1 = c1 + k1;
#define TF_R(a) { x0 += x1; x1 = rotl32(x1, a); x1 ^= x0; }
  TF_R(13) TF_R(15) TF_R(26) TF_R(6)   x0 += k1;  x1 += ks2 + 1u;
  TF_R(17) TF_R(29) TF_R(16) TF_R(24)  x0 += ks2; x1 += k0 + 2u;
  TF_R(13) TF_R(15) TF_R(26) TF_R(6)   x0 += k0;  x1 += k1 + 3u;
  TF_R(17) TF_R(29) TF_R(16) TF_R(24)  x0 += k1;  x1 += ks2 + 4u;
  TF_R(13) TF_R(15) TF_R(26) TF_R(6)   x0 += ks2; x1 += k0 + 5u;
#undef TF_R
  o0 = x0; o1 = x1;
}

__device__ __forceinline__ bool keep_elem(unsigned j) {
  unsigned o0, o1;
  tf2x32(0u, 42u, 0u, j, o0, o1);
  unsigned bits = o0 ^ o1;
  float uf = __uint_as_float((bits >> 9) | 0x3f800000u) - 1.0f;
  return uf < 0.7f;
}

// --- prep: bucket fill | fp16 pack of x | fp16 transposed pack of W (one grid) ---
__global__ __launch_bounds__(256) void prep(const float* __restrict__ x,
                                            __half* __restrict__ xh,
                                            const int* __restrict__ src,
                                            const int* __restrict__ dst,
                                            const float* __restrict__ Wself,
                                            const float* __restrict__ Wneigh,
                                            float* __restrict__ Wp,
                                            int* __restrict__ cursor,
                                            int* __restrict__ bucket) {
  int b = blockIdx.x;
  if (b < FILL_BLOCKS) {
    int e = b * 256 + threadIdx.x;
    int d = dst[e];
    int pos = atomicAdd(&cursor[d], 1);
    if (pos < CAP) bucket[d * CAP + pos] = src[e];
  } else if (b < FILL_BLOCKS + PACK_BLOCKS) {
    int i = (b - FILL_BLOCKS) * 256 + threadIdx.x;   // one float4 -> 8B half4
    float4 v = ((const float4*)x)[i];
    __half2 h01 = __floats2half2_rn(v.x, v.y);
    __half2 h23 = __floats2half2_rn(v.z, v.w);
    float2 o;
    o.x = __uint_as_float(*(const unsigned*)&h01);
    o.y = __uint_as_float(*(const unsigned*)&h23);
    ((float2*)xh)[i] = o;
  } else {
    // W pack, coalesced-read layout: dword (h,c,k2) -> float4 slot [kc][cc][cg], part k2&3
    int idx = (b - FILL_BLOCKS - PACK_BLOCKS) * 256 + threadIdx.x;  // [0, 16384)
    int h = idx >> 13, rem = idx & 8191;
    int k2 = rem >> 7, c = rem & 127;
    const float* Ws = h ? Wneigh : Wself;
    __half2 hh = __floats2half2_rn(Ws[(k2 * 2) * 128 + c], Ws[(k2 * 2 + 1) * 128 + c]);
    int kc = k2 >> 2, cc = c & 7, cg = c >> 3;
    int nd = (((kc * 8 + cc) * 16 + cg) << 2) | (k2 & 3);
    Wp[h * 8192 + nd] = __builtin_bit_cast(float, hh);
  }
}

// ---- gather: one 64-lane wave per node; zero LDS; 8 loads in flight ----
// Also generates the dropout bitmask (threefry+ballot) — hides under vmcnt stalls.
// Writes the fp16 mean row (256B) OVER the node's consumed bucket row.
__global__ __launch_bounds__(256) void gather_kernel(const __half* __restrict__ xh,
                                                     const int* __restrict__ cursor,
                                                     const int* bucket,
                                                     __half* seg,
                                                     unsigned long long* __restrict__ mask64) {
  const int w = threadIdx.x >> 6, li = threadIdx.x & 63;
  const int n = blockIdx.x * 4 + w;          // 12500 * 4 = 50000 exactly
  int deg = cursor[n]; deg = deg < CAP ? deg : CAP;
  float sx = 0.f, sy = 0.f;
  const unsigned* xr = (const unsigned*)xh;  // dword = half2; row stride 64
  const int* ep = bucket + (size_t)n * CAP;  // wave-uniform -> scalar loads
  for (int j0 = 0; j0 < deg; j0 += 8) {
    int idx[8];
#pragma unroll
    for (int k = 0; k < 8; ++k) {
      int j = j0 + k;
      idx[k] = ep[j < deg ? j : deg - 1];    // clamped -> always a valid slot
    }
    unsigned u[8];
#pragma unroll
    for (int k = 0; k < 8; ++k)
      u[k] = xr[(size_t)idx[k] * 64 + li];   // 8 independent coalesced dwords
#pragma unroll
    for (int k = 0; k < 8; ++k)
      if (j0 + k < deg) {
        float2 f = __half22float2(__builtin_bit_cast(__half2, u[k]));
        sx += f.x; sy += f.y;
      }
  }
  // dropout mask: block covers elements [blockIdx*1024, +1024) = 16 u64 words
  {
    unsigned j0 = (unsigned)blockIdx.x * 1024u + (unsigned)w * 256u;
#pragma unroll
    for (int r = 0; r < 4; ++r) {
      unsigned j = j0 + (unsigned)r * 64u + (unsigned)li;
      unsigned long long b = __ballot(keep_elem(j));
      if (li == 0) mask64[(size_t)blockIdx.x * 16 + w * 4 + r] = b;
    }
  }
  float iv = 1.0f / (float)(deg > 1 ? deg : 1);
  __half2 r = __floats2half2_rn(sx * iv, sy * iv);
  ((unsigned*)seg)[(size_t)n * 64 + li] = __builtin_bit_cast(unsigned, r);
}

// ---- gemm: stage xh/seg rows -> dual fp16-dot2 GEMM -> mask epilogue ----
__global__ __launch_bounds__(256) void gemm_kernel(
    const __half* __restrict__ xh, const __half* __restrict__ seg,
    const float* __restrict__ Wp, const float* __restrict__ bias,
    const unsigned* __restrict__ mask, float* __restrict__ out) {
  __shared__ __align__(16) __half Ah[2][NPB][APAD_H];   // 8.7 KB
  __shared__ float rowss[2][NPB];

  const int t = threadIdx.x;
  const int row0 = blockIdx.x * NPB;

  // ---- stage self + mean rows (2 arrays x 256 granules, coalesced) ----
#pragma unroll
  for (int k = 0; k < 2; ++k) {
    int q = k * 256 + t;
    int arr = q >> 8, rem = q & 255;
    int row = rem >> 4, f8 = rem & 15;
    int grow = row0 + row;                   // 3125*16 = 50000: always in range
    const __half* sp = arr ? seg : xh;
    *(float4*)&Ah[arr][row][f8 * 8] = ((const float4*)sp)[(size_t)grow * 16 + f8];
  }
  __syncthreads();

  // ---- GEMM phase: fp16 dot2, f32 accumulate; W reads coalesced ----
  const int h = t >> 7, rg = (t >> 4) & 7, cg = t & 15;
  const float4* Ab4 = (const float4*)&Ah[h][0][0];    // row stride 17 float4
  const float4* Wp4 = (const float4*)(Wp + h * 8192); // [kc][c][cg] float4s

  float acc[2][8];
#pragma unroll
  for (int i = 0; i < 2; ++i)
#pragma unroll
    for (int c = 0; c < 8; ++c) acc[i][c] = 0.0f;

  for (int kc = 0; kc < 16; ++kc) {          // 8 k-values (4 half2) per chunk
    float4 wv[8];
#pragma unroll
    for (int c = 0; c < 8; ++c)
      wv[c] = Wp4[(kc * 8 + c) * 16 + cg];   // lanes cg: 256B contiguous
#pragma unroll
    for (int i = 0; i < 2; ++i) {
      float4 av = Ab4[(rg * 2 + i) * 17 + kc];
#pragma unroll
      for (int c = 0; c < 8; ++c) {
        float s = acc[i][c];
        s = fd2(av.x, wv[c].x, s);
        s = fd2(av.y, wv[c].y, s);
        s = fd2(av.z, wv[c].z, s);
        s = fd2(av.w, wv[c].w, s);
        acc[i][c] = s;
      }
    }
  }

  // ---- epilogue: +bias, ELU, dropout (precomputed mask), l2norm, store ----
  float4 b0 = ((const float4*)bias)[h * 32 + cg * 2];
  float4 b1 = ((const float4*)bias)[h * 32 + cg * 2 + 1];
  float bb[8] = {b0.x, b0.y, b0.z, b0.w, b1.x, b1.y, b1.z, b1.w};

  float ss[2];
#pragma unroll
  for (int i = 0; i < 2; ++i) {
    unsigned n = row0 + rg * 2 + i;
    unsigned mw = mask[n * 8u + (unsigned)h * 4u + (cg >> 2)];
    unsigned sh = (cg & 3) * 8;
    ss[i] = 0.0f;
#pragma unroll
    for (int c = 0; c < 8; ++c) {
      float val = acc[i][c] + bb[c];
      val = (val > 0.0f) ? val : expm1f(val);
      val = ((mw >> (sh + c)) & 1u) ? val * (1.0f / 0.7f) : 0.0f;
      acc[i][c] = val;
      ss[i] = fmaf(val, val, ss[i]);
    }
  }
#pragma unroll
  for (int d = 1; d < 16; d <<= 1)
#pragma unroll
    for (int i = 0; i < 2; ++i) ss[i] += __shfl_xor(ss[i], d, 16);
  if (cg == 0) {
#pragma unroll
    for (int i = 0; i < 2; ++i) rowss[h][rg * 2 + i] = ss[i];
  }
  __syncthreads();

#pragma unroll
  for (int i = 0; i < 2; ++i) {
    int lrow = rg * 2 + i;
    float scale = rsqrtf(fmaxf(rowss[0][lrow] + rowss[1][lrow], 1e-12f));
    size_t n = (size_t)(row0 + lrow);
    float* op = out + n * 256 + h * 128 + cg * 8;
    float4 o0, o1;
    o0.x = acc[i][0] * scale; o0.y = acc[i][1] * scale;
    o0.z = acc[i][2] * scale; o0.w = acc[i][3] * scale;
    o1.x = acc[i][4] * scale; o1.y = acc[i][5] * scale;
    o1.z = acc[i][6] * scale; o1.w = acc[i][7] * scale;
    *(float4*)op = o0;
    *(float4*)(op + 4) = o1;
  }
}

extern "C" void kernel_launch(void* const* d_in, const int* in_sizes, int n_in,
                              void* d_out, int out_size, void* d_ws, size_t ws_size,
                              hipStream_t stream) {
  const float* x      = (const float*)d_in[0];
  const float* Wself  = (const float*)d_in[1];
  const float* Wneigh = (const float*)d_in[2];
  const float* bias   = (const float*)d_in[3];
  const int*   src    = (const int*)d_in[4];   // jnp.int64 degrades to int32 (x64 off)
  const int*   dst    = (const int*)d_in[5];
  float* out = (float*)d_out;

  char* p = (char*)d_ws;
  int*      cursor = (int*)p;                    // 200,000 B (pad 200,704)
  int*      bucket = (int*)(p + 200704);         // 12,800,000 B  (gather overwrites
  __half*   seg    = (__half*)(p + 200704);      //   consumed rows with fp16 means)
  __half*   xh     = (__half*)(p + 13001728);    // 12,800,000 B
  unsigned* mask   = (unsigned*)(p + 25801728);  // 1,600,000 B (8B-aligned)
  float*    Wp     = (float*)(p + 27401728);     // 65,536 B (end ~27.5 MB)

  hipMemsetAsync(cursor, 0, 200000, stream);
  prep<<<FILL_BLOCKS + PACK_BLOCKS + WPACK_BLOCKS, 256, 0, stream>>>(
      x, xh, src, dst, Wself, Wneigh, Wp, cursor, bucket);
  gather_kernel<<<N_NODES / 4, 256, 0, stream>>>(xh, cursor, bucket, seg,
                                                 (unsigned long long*)mask);
  gemm_kernel  <<<NBLK, 256, 0, stream>>>(xh, seg, Wp, bias, mask, out);
}

// Round 16
// 168.255 us; speedup vs baseline: 1.0319x; 1.0319x over previous
//
#include <hip/hip_runtime.h>
#include <hip/hip_fp16.h>
#include <math.h>

#define N_NODES 50000
#define F_DIM   128
#define E_EDGES 800000
#define NPB     32      // nodes per gemm block -> 1563 blocks (last block 16 rows)
#define NBLK    1563
#define CAP     64      // bucket capacity per node
#define APAD_H  136     // padded row stride in halves (272 B)
#define FILL_BLOCKS (E_EDGES / 256)            // 3125
#define PACK_BLOCKS ((N_NODES * F_DIM) / 1024) // 6250
#define WPACK_BLOCKS 64                        // 2*128*64 half2 words / 256

typedef _Float16 h2v __attribute__((ext_vector_type(2)));

// fdot2: 2-way fp16 dot with f32 accumulate (falls back to cvt+fma if unavailable)
__device__ __forceinline__ float fd2(float a, float b, float c) {
#if __has_builtin(__builtin_amdgcn_fdot2)
  return __builtin_amdgcn_fdot2(__builtin_bit_cast(h2v, a),
                                __builtin_bit_cast(h2v, b), c, false);
#else
  float2 fa = __half22float2(__builtin_bit_cast(__half2, a));
  float2 fb = __half22float2(__builtin_bit_cast(__half2, b));
  return fmaf(fa.x, fb.x, fmaf(fa.y, fb.y, c));
#endif
}

// ---------------- JAX threefry (partitionable path, o0^o1) — verified r2 ----------------
__device__ __forceinline__ unsigned rotl32(unsigned x, int d) {
  return (x << d) | (x >> (32 - d));
}

__device__ __forceinline__ void tf2x32(unsigned k0, unsigned k1,
                                       unsigned c0, unsigned c1,
                                       unsigned &o0, unsigned &o1) {
  unsigned ks2 = k0 ^ k1 ^ 0x1BD11BDAu;
  unsigned x0 = c0 + k0, x1 = c1 + k1;
#define TF_R(a) { x0 += x1; x1 = rotl32(x1, a); x1 ^= x0; }
  TF_R(13) TF_R(15) TF_R(26) TF_R(6)   x0 += k1;  x1 += ks2 + 1u;
  TF_R(17) TF_R(29) TF_R(16) TF_R(24)  x0 += ks2; x1 += k0 + 2u;
  TF_R(13) TF_R(15) TF_R(26) TF_R(6)   x0 += k0;  x1 += k1 + 3u;
  TF_R(17) TF_R(29) TF_R(16) TF_R(24)  x0 += k1;  x1 += ks2 + 4u;
  TF_R(13) TF_R(15) TF_R(26) TF_R(6)   x0 += ks2; x1 += k0 + 5u;
#undef TF_R
  o0 = x0; o1 = x1;
}

__device__ __forceinline__ bool keep_elem(unsigned j) {
  unsigned o0, o1;
  tf2x32(0u, 42u, 0u, j, o0, o1);
  unsigned bits = o0 ^ o1;
  float uf = __uint_as_float((bits >> 9) | 0x3f800000u) - 1.0f;
  return uf < 0.7f;
}

// --- prep: bucket fill | fp16 pack of x | fp16 transposed pack of W (one grid) ---
__global__ __launch_bounds__(256) void prep(const float* __restrict__ x,
                                            __half* __restrict__ xh,
                                            const int* __restrict__ src,
                                            const int* __restrict__ dst,
                                            const float* __restrict__ Wself,
                                            const float* __restrict__ Wneigh,
                                            float* __restrict__ Wp,
                                            int* __restrict__ cursor,
                                            int* __restrict__ bucket) {
  int b = blockIdx.x;
  if (b < FILL_BLOCKS) {
    int e = b * 256 + threadIdx.x;
    int d = dst[e];
    int pos = atomicAdd(&cursor[d], 1);
    if (pos < CAP) bucket[d * CAP + pos] = src[e];
  } else if (b < FILL_BLOCKS + PACK_BLOCKS) {
    int i = (b - FILL_BLOCKS) * 256 + threadIdx.x;   // one float4 -> 8B half4
    float4 v = ((const float4*)x)[i];
    __half2 h01 = __floats2half2_rn(v.x, v.y);
    __half2 h23 = __floats2half2_rn(v.z, v.w);
    float2 o;
    o.x = __uint_as_float(*(const unsigned*)&h01);
    o.y = __uint_as_float(*(const unsigned*)&h23);
    ((float2*)xh)[i] = o;
  } else {
    // W pack: dword (h,c,k2) -> float4 slot [kc][cc=c&3][cg=c>>2], lane part k2&3
    int idx = (b - FILL_BLOCKS - PACK_BLOCKS) * 256 + threadIdx.x;  // [0, 16384)
    int h = idx >> 13, rem = idx & 8191;
    int k2 = rem >> 7, c = rem & 127;
    const float* Ws = h ? Wneigh : Wself;
    __half2 hh = __floats2half2_rn(Ws[(k2 * 2) * 128 + c], Ws[(k2 * 2 + 1) * 128 + c]);
    int kc = k2 >> 2, cc = c & 3, cg = c >> 2;
    int nd = (((kc * 4 + cc) * 32 + cg) << 2) | (k2 & 3);
    Wp[h * 8192 + nd] = __builtin_bit_cast(float, hh);
  }
}

// ---- gather: one 64-lane wave per node; zero LDS; 8 loads in flight ----
// Also generates the dropout bitmask (threefry+ballot) — hides under vmcnt stalls.
// Writes the fp16 mean row (256B) OVER the node's consumed bucket row.
__global__ __launch_bounds__(256) void gather_kernel(const __half* __restrict__ xh,
                                                     const int* __restrict__ cursor,
                                                     const int* bucket,
                                                     __half* seg,
                                                     unsigned long long* __restrict__ mask64) {
  const int w = threadIdx.x >> 6, li = threadIdx.x & 63;
  const int n = blockIdx.x * 4 + w;          // 12500 * 4 = 50000 exactly
  int deg = cursor[n]; deg = deg < CAP ? deg : CAP;
  float sx = 0.f, sy = 0.f;
  const unsigned* xr = (const unsigned*)xh;  // dword = half2; row stride 64
  const int* ep = bucket + (size_t)n * CAP;  // wave-uniform -> scalar loads
  for (int j0 = 0; j0 < deg; j0 += 8) {
    int idx[8];
#pragma unroll
    for (int k = 0; k < 8; ++k) {
      int j = j0 + k;
      idx[k] = ep[j < deg ? j : deg - 1];    // clamped -> always a valid slot
    }
    unsigned u[8];
#pragma unroll
    for (int k = 0; k < 8; ++k)
      u[k] = xr[(size_t)idx[k] * 64 + li];   // 8 independent coalesced dwords
#pragma unroll
    for (int k = 0; k < 8; ++k)
      if (j0 + k < deg) {
        float2 f = __half22float2(__builtin_bit_cast(__half2, u[k]));
        sx += f.x; sy += f.y;
      }
  }
  // dropout mask: block covers elements [blockIdx*1024, +1024) = 16 u64 words
  {
    unsigned j0 = (unsigned)blockIdx.x * 1024u + (unsigned)w * 256u;
#pragma unroll
    for (int r = 0; r < 4; ++r) {
      unsigned j = j0 + (unsigned)r * 64u + (unsigned)li;
      unsigned long long b = __ballot(keep_elem(j));
      if (li == 0) mask64[(size_t)blockIdx.x * 16 + w * 4 + r] = b;
    }
  }
  float iv = 1.0f / (float)(deg > 1 ? deg : 1);
  __half2 r = __floats2half2_rn(sx * iv, sy * iv);
  ((unsigned*)seg)[(size_t)n * 64 + li] = __builtin_bit_cast(unsigned, r);
}

// ---- gemm: 512 threads on a 32-row tile; 4 rows x 4 cols per thread ----
// h = t>>8 (half), rg = (t>>5)&7 (4 rows each), cg = t&31 (4 cols each).
__global__ __launch_bounds__(512) void gemm_kernel(
    const __half* __restrict__ xh, const __half* __restrict__ seg,
    const float* __restrict__ Wp, const float* __restrict__ bias,
    const unsigned* __restrict__ mask, float* __restrict__ out) {
  __shared__ __align__(16) __half Ah[2][NPB][APAD_H];   // 17.4 KB
  __shared__ float rowss[2][NPB];

  const int t = threadIdx.x;
  const int row0 = blockIdx.x * NPB;

  // ---- stage self + mean rows (1024 x 16B granules, 2/thread, coalesced) ----
#pragma unroll
  for (int k = 0; k < 2; ++k) {
    int q = k * 512 + t;
    int arr = q >> 9, rem = q & 511;
    int row = rem >> 4, f8 = rem & 15;
    int grow = row0 + row;
    if (grow > N_NODES - 1) grow = N_NODES - 1;
    const __half* sp = arr ? seg : xh;
    *(float4*)&Ah[arr][row][f8 * 8] = ((const float4*)sp)[(size_t)grow * 16 + f8];
  }
  __syncthreads();

  // ---- GEMM phase: fp16 dot2, f32 accumulate; coalesced W (512B per 32 lanes) ----
  const int h = t >> 8, rg = (t >> 5) & 7, cg = t & 31;
  const float4* Ab4 = (const float4*)&Ah[h][0][0];    // row stride 17 float4
  const float4* Wp4 = (const float4*)Wp + h * 2048;   // [kc][cc][cg] float4s

  float acc[4][4];
#pragma unroll
  for (int i = 0; i < 4; ++i)
#pragma unroll
    for (int c = 0; c < 4; ++c) acc[i][c] = 0.0f;

  for (int kc = 0; kc < 16; ++kc) {          // 8 k-values (4 half2) per chunk
    float4 wv[4];
#pragma unroll
    for (int c = 0; c < 4; ++c)
      wv[c] = Wp4[(kc * 4 + c) * 32 + cg];
#pragma unroll
    for (int i = 0; i < 4; ++i) {
      float4 av = Ab4[(rg * 4 + i) * 17 + kc];
#pragma unroll
      for (int c = 0; c < 4; ++c) {
        float s = acc[i][c];
        s = fd2(av.x, wv[c].x, s);
        s = fd2(av.y, wv[c].y, s);
        s = fd2(av.z, wv[c].z, s);
        s = fd2(av.w, wv[c].w, s);
        acc[i][c] = s;
      }
    }
  }

  // ---- epilogue: +bias, ELU, dropout (precomputed mask), l2norm, store ----
  float4 b4 = ((const float4*)bias)[h * 32 + cg];
  float bb[4] = {b4.x, b4.y, b4.z, b4.w};

  float ss[4];
#pragma unroll
  for (int i = 0; i < 4; ++i) {
    unsigned n = row0 + rg * 4 + i;
    unsigned mw = (n < N_NODES) ? mask[n * 8u + (unsigned)h * 4u + (cg >> 3)] : 0u;
    unsigned sh = (cg & 7) * 4;
    ss[i] = 0.0f;
#pragma unroll
    for (int c = 0; c < 4; ++c) {
      float val = acc[i][c] + bb[c];
      val = (val > 0.0f) ? val : expm1f(val);
      val = ((mw >> (sh + c)) & 1u) ? val * (1.0f / 0.7f) : 0.0f;
      acc[i][c] = val;
      ss[i] = fmaf(val, val, ss[i]);
    }
  }
#pragma unroll
  for (int d = 1; d < 32; d <<= 1)
#pragma unroll
    for (int i = 0; i < 4; ++i) ss[i] += __shfl_xor(ss[i], d, 32);
  if (cg == 0) {
#pragma unroll
    for (int i = 0; i < 4; ++i) rowss[h][rg * 4 + i] = ss[i];
  }
  __syncthreads();

#pragma unroll
  for (int i = 0; i < 4; ++i) {
    int lrow = rg * 4 + i;
    size_t n = (size_t)(row0 + lrow);
    if (n < N_NODES) {
      float scale = rsqrtf(fmaxf(rowss[0][lrow] + rowss[1][lrow], 1e-12f));
      float* op = out + n * 256 + h * 128 + cg * 4;
      float4 o;
      o.x = acc[i][0] * scale; o.y = acc[i][1] * scale;
      o.z = acc[i][2] * scale; o.w = acc[i][3] * scale;
      *(float4*)op = o;
    }
  }
}

extern "C" void kernel_launch(void* const* d_in, const int* in_sizes, int n_in,
                              void* d_out, int out_size, void* d_ws, size_t ws_size,
                              hipStream_t stream) {
  const float* x      = (const float*)d_in[0];
  const float* Wself  = (const float*)d_in[1];
  const float* Wneigh = (const float*)d_in[2];
  const float* bias   = (const float*)d_in[3];
  const int*   src    = (const int*)d_in[4];   // jnp.int64 degrades to int32 (x64 off)
  const int*   dst    = (const int*)d_in[5];
  float* out = (float*)d_out;

  char* p = (char*)d_ws;
  int*      cursor = (int*)p;                    // 200,000 B (pad 200,704)
  int*      bucket = (int*)(p + 200704);         // 12,800,000 B  (gather overwrites
  __half*   seg    = (__half*)(p + 200704);      //   consumed rows with fp16 means)
  __half*   xh     = (__half*)(p + 13001728);    // 12,800,000 B
  unsigned* mask   = (unsigned*)(p + 25801728);  // 1,600,000 B (8B-aligned)
  float*    Wp     = (float*)(p + 27401728);     // 65,536 B (end ~27.5 MB)

  hipMemsetAsync(cursor, 0, 200000, stream);
  prep<<<FILL_BLOCKS + PACK_BLOCKS + WPACK_BLOCKS, 256, 0, stream>>>(
      x, xh, src, dst, Wself, Wneigh, Wp, cursor, bucket);
  gather_kernel<<<N_NODES / 4, 256, 0, stream>>>(xh, cursor, bucket, seg,
                                                 (unsigned long long*)mask);
  gemm_kernel  <<<NBLK, 512, 0, stream>>>(xh, seg, Wp, bias, mask, out);
}

// Round 17
// 166.520 us; speedup vs baseline: 1.0426x; 1.0104x over previous
//
#include <hip/hip_runtime.h>
#include <hip/hip_fp16.h>
#include <math.h>

#define N_NODES 50000
#define F_DIM   128
#define E_EDGES 800000
#define NPB     64      // nodes per gemm block -> 782 blocks (last block 16 rows)
#define NBLK    782
#define CAP     64      // bucket capacity per node
#define APAD_H  136     // padded row stride in halves (272 B)
#define FILL_BLOCKS (E_EDGES / 256)            // 3125
#define PACK_BLOCKS ((N_NODES * F_DIM) / 1024) // 6250
#define WPACK_BLOCKS 64                        // 2*128*64 half2 words / 256

typedef _Float16 h2v __attribute__((ext_vector_type(2)));

// fdot2: 2-way fp16 dot with f32 accumulate (falls back to cvt+fma if unavailable)
__device__ __forceinline__ float fd2(float a, float b, float c) {
#if __has_builtin(__builtin_amdgcn_fdot2)
  return __builtin_amdgcn_fdot2(__builtin_bit_cast(h2v, a),
                                __builtin_bit_cast(h2v, b), c, false);
#else
  float2 fa = __half22float2(__builtin_bit_cast(__half2, a));
  float2 fb = __half22float2(__builtin_bit_cast(__half2, b));
  return fmaf(fa.x, fb.x, fmaf(fa.y, fb.y, c));
#endif
}

// ---------------- JAX threefry (partitionable path, o0^o1) — verified r2 ----------------
__device__ __forceinline__ unsigned rotl32(unsigned x, int d) {
  return (x << d) | (x >> (32 - d));
}

__device__ __forceinline__ void tf2x32(unsigned k0, unsigned k1,
                                       unsigned c0, unsigned c1,
                                       unsigned &o0, unsigned &o1) {
  unsigned ks2 = k0 ^ k1 ^ 0x1BD11BDAu;
  unsigned x0 = c0 + k0, x1 = c1 + k1;
#define TF_R(a) { x0 += x1; x1 = rotl32(x1, a); x1 ^= x0; }
  TF_R(13) TF_R(15) TF_R(26) TF_R(6)   x0 += k1;  x1 += ks2 + 1u;
  TF_R(17) TF_R(29) TF_R(16) TF_R(24)  x0 += ks2; x1 += k0 + 2u;
  TF_R(13) TF_R(15) TF_R(26) TF_R(6)   x0 += k0;  x1 += k1 + 3u;
  TF_R(17) TF_R(29) TF_R(16) TF_R(24)  x0 += k1;  x1 += ks2 + 4u;
  TF_R(13) TF_R(15) TF_R(26) TF_R(6)   x0 += ks2; x1 += k0 + 5u;
#undef TF_R
  o0 = x0; o1 = x1;
}

__device__ __forceinline__ bool keep_elem(unsigned j) {
  unsigned o0, o1;
  tf2x32(0u, 42u, 0u, j, o0, o1);
  unsigned bits = o0 ^ o1;
  float uf = __uint_as_float((bits >> 9) | 0x3f800000u) - 1.0f;
  return uf < 0.7f;
}

// --- prep: bucket fill (u16) | fp16 pack of x | fp16 transposed pack of W ---
__global__ __launch_bounds__(256) void prep(const float* __restrict__ x,
                                            __half* __restrict__ xh,
                                            const int* __restrict__ src,
                                            const int* __restrict__ dst,
                                            const float* __restrict__ Wself,
                                            const float* __restrict__ Wneigh,
                                            float* __restrict__ Wp,
                                            int* __restrict__ cursor,
                                            unsigned short* __restrict__ bucket) {
  int b = blockIdx.x;
  if (b < FILL_BLOCKS) {
    int e = b * 256 + threadIdx.x;
    int d = dst[e];
    int pos = atomicAdd(&cursor[d], 1);
    if (pos < CAP) bucket[d * CAP + pos] = (unsigned short)src[e];
  } else if (b < FILL_BLOCKS + PACK_BLOCKS) {
    int i = (b - FILL_BLOCKS) * 256 + threadIdx.x;   // one float4 -> 8B half4
    float4 v = ((const float4*)x)[i];
    __half2 h01 = __floats2half2_rn(v.x, v.y);
    __half2 h23 = __floats2half2_rn(v.z, v.w);
    float2 o;
    o.x = __uint_as_float(*(const unsigned*)&h01);
    o.y = __uint_as_float(*(const unsigned*)&h23);
    ((float2*)xh)[i] = o;
  } else {
    // W pack: dword (h,c,k2) -> float4 slot [kc][cc=c&3][cg=c>>2], lane part k2&3
    int idx = (b - FILL_BLOCKS - PACK_BLOCKS) * 256 + threadIdx.x;  // [0, 16384)
    int h = idx >> 13, rem = idx & 8191;
    int k2 = rem >> 7, c = rem & 127;
    const float* Ws = h ? Wneigh : Wself;
    __half2 hh = __floats2half2_rn(Ws[(k2 * 2) * 128 + c], Ws[(k2 * 2 + 1) * 128 + c]);
    int kc = k2 >> 2, cc = c & 3, cg = c >> 2;
    int nd = (((kc * 4 + cc) * 32 + cg) << 2) | (k2 & 3);
    Wp[h * 8192 + nd] = __builtin_bit_cast(float, hh);
  }
}

// ---- gather: one 64-lane wave per node; zero LDS; 8 loads in flight ----
// Also generates the dropout bitmask (threefry+ballot) — hides under vmcnt stalls.
__global__ __launch_bounds__(256) void gather_kernel(const __half* __restrict__ xh,
                                                     const int* __restrict__ cursor,
                                                     const unsigned short* __restrict__ bucket,
                                                     __half* __restrict__ seg,
                                                     unsigned long long* __restrict__ mask64) {
  const int w = threadIdx.x >> 6, li = threadIdx.x & 63;
  const int n = blockIdx.x * 4 + w;          // 12500 * 4 = 50000 exactly
  int deg = cursor[n]; deg = deg < CAP ? deg : CAP;
  float sx = 0.f, sy = 0.f;
  const unsigned* xr = (const unsigned*)xh;  // dword = half2; row stride 64
  const unsigned short* ep = bucket + (size_t)n * CAP;  // wave-uniform
  for (int j0 = 0; j0 < deg; j0 += 8) {
    int idx[8];
#pragma unroll
    for (int k = 0; k < 8; ++k) {
      int j = j0 + k;
      idx[k] = ep[j < deg ? j : deg - 1];    // clamped -> always a valid slot
    }
    unsigned u[8];
#pragma unroll
    for (int k = 0; k < 8; ++k)
      u[k] = xr[(size_t)idx[k] * 64 + li];   // 8 independent coalesced dwords
#pragma unroll
    for (int k = 0; k < 8; ++k)
      if (j0 + k < deg) {
        float2 f = __half22float2(__builtin_bit_cast(__half2, u[k]));
        sx += f.x; sy += f.y;
      }
  }
  // dropout mask: block covers elements [blockIdx*1024, +1024) = 16 u64 words
  {
    unsigned j0 = (unsigned)blockIdx.x * 1024u + (unsigned)w * 256u;
#pragma unroll
    for (int r = 0; r < 4; ++r) {
      unsigned j = j0 + (unsigned)r * 64u + (unsigned)li;
      unsigned long long b = __ballot(keep_elem(j));
      if (li == 0) mask64[(size_t)blockIdx.x * 16 + w * 4 + r] = b;
    }
  }
  float iv = 1.0f / (float)(deg > 1 ? deg : 1);
  __half2 r = __floats2half2_rn(sx * iv, sy * iv);
  ((unsigned*)seg)[(size_t)n * 64 + li] = __builtin_bit_cast(unsigned, r);
}

// ---- gemm: 512 threads on a 64-row tile; 8 rows x 4 cols per thread ----
// h = t>>8 (half), rg = (t>>5)&7 (8 rows each), cg = t&31 (4 cols each).
__global__ __launch_bounds__(512) void gemm_kernel(
    const __half* __restrict__ xh, const __half* __restrict__ seg,
    const float* __restrict__ Wp, const float* __restrict__ bias,
    const unsigned* __restrict__ mask, float* __restrict__ out) {
  __shared__ __align__(16) __half Ah[2][NPB][APAD_H];   // 34.8 KB
  __shared__ float rowss[2][NPB];

  const int t = threadIdx.x;
  const int row0 = blockIdx.x * NPB;

  // ---- stage self + mean rows (2048 x 16B granules, 4/thread, coalesced) ----
#pragma unroll
  for (int k = 0; k < 4; ++k) {
    int q = k * 512 + t;
    int arr = q >> 10, rem = q & 1023;
    int row = rem >> 4, f8 = rem & 15;
    int grow = row0 + row;
    if (grow > N_NODES - 1) grow = N_NODES - 1;
    const __half* sp = arr ? seg : xh;
    *(float4*)&Ah[arr][row][f8 * 8] = ((const float4*)sp)[(size_t)grow * 16 + f8];
  }
  __syncthreads();

  // ---- GEMM phase: fp16 dot2, f32 accumulate; coalesced W (512B per 32 lanes) ----
  const int h = t >> 8, rg = (t >> 5) & 7, cg = t & 31;
  const float4* Ab4 = (const float4*)&Ah[h][0][0];    // row stride 17 float4
  const float4* Wp4 = (const float4*)Wp + h * 2048;   // [kc][cc][cg] float4s

  float acc[8][4];
#pragma unroll
  for (int i = 0; i < 8; ++i)
#pragma unroll
    for (int c = 0; c < 4; ++c) acc[i][c] = 0.0f;

  for (int kc = 0; kc < 16; ++kc) {          // 8 k-values (4 half2) per chunk
    float4 wv[4];
#pragma unroll
    for (int c = 0; c < 4; ++c)
      wv[c] = Wp4[(kc * 4 + c) * 32 + cg];
#pragma unroll
    for (int i = 0; i < 8; ++i) {
      float4 av = Ab4[(rg * 8 + i) * 17 + kc];
#pragma unroll
      for (int c = 0; c < 4; ++c) {
        float s = acc[i][c];
        s = fd2(av.x, wv[c].x, s);
        s = fd2(av.y, wv[c].y, s);
        s = fd2(av.z, wv[c].z, s);
        s = fd2(av.w, wv[c].w, s);
        acc[i][c] = s;
      }
    }
  }

  // ---- epilogue: +bias, ELU, dropout (precomputed mask), l2norm, store ----
  float4 b4 = ((const float4*)bias)[h * 32 + cg];
  float bb[4] = {b4.x, b4.y, b4.z, b4.w};

  float ss[8];
#pragma unroll
  for (int i = 0; i < 8; ++i) {
    unsigned n = row0 + rg * 8 + i;
    unsigned mw = (n < N_NODES) ? mask[n * 8u + (unsigned)h * 4u + (cg >> 3)] : 0u;
    unsigned sh = (cg & 7) * 4;
    ss[i] = 0.0f;
#pragma unroll
    for (int c = 0; c < 4; ++c) {
      float val = acc[i][c] + bb[c];
      val = (val > 0.0f) ? val : expm1f(val);
      val = ((mw >> (sh + c)) & 1u) ? val * (1.0f / 0.7f) : 0.0f;
      acc[i][c] = val;
      ss[i] = fmaf(val, val, ss[i]);
    }
  }
#pragma unroll
  for (int d = 1; d < 32; d <<= 1)
#pragma unroll
    for (int i = 0; i < 8; ++i) ss[i] += __shfl_xor(ss[i], d, 32);
  if (cg == 0) {
#pragma unroll
    for (int i = 0; i < 8; ++i) rowss[h][rg * 8 + i] = ss[i];
  }
  __syncthreads();

#pragma unroll
  for (int i = 0; i < 8; ++i) {
    int lrow = rg * 8 + i;
    size_t n = (size_t)(row0 + lrow);
    if (n < N_NODES) {
      float scale = rsqrtf(fmaxf(rowss[0][lrow] + rowss[1][lrow], 1e-12f));
      float* op = out + n * 256 + h * 128 + cg * 4;
      float4 o;
      o.x = acc[i][0] * scale; o.y = acc[i][1] * scale;
      o.z = acc[i][2] * scale; o.w = acc[i][3] * scale;
      *(float4*)op = o;
    }
  }
}

extern "C" void kernel_launch(void* const* d_in, const int* in_sizes, int n_in,
                              void* d_out, int out_size, void* d_ws, size_t ws_size,
                              hipStream_t stream) {
  const float* x      = (const float*)d_in[0];
  const float* Wself  = (const float*)d_in[1];
  const float* Wneigh = (const float*)d_in[2];
  const float* bias   = (const float*)d_in[3];
  const int*   src    = (const int*)d_in[4];   // jnp.int64 degrades to int32 (x64 off)
  const int*   dst    = (const int*)d_in[5];
  float* out = (float*)d_out;

  char* p = (char*)d_ws;
  int*            cursor = (int*)p;                       // 200,000 B (pad 200,704)
  unsigned short* bucket = (unsigned short*)(p + 200704); // 6,400,000 B
  __half*         seg    = (__half*)(p + 6600704);        // 12,800,000 B
  __half*         xh     = (__half*)(p + 19400704);       // 12,800,000 B
  unsigned*       mask   = (unsigned*)(p + 32200704);     // 1,600,000 B (8B-aligned)
  float*          Wp     = (float*)(p + 33800704);        // 65,536 B (end ~33.9 MB)

  hipMemsetAsync(cursor, 0, 200000, stream);
  prep<<<FILL_BLOCKS + PACK_BLOCKS + WPACK_BLOCKS, 256, 0, stream>>>(
      x, xh, src, dst, Wself, Wneigh, Wp, cursor, bucket);
  gather_kernel<<<N_NODES / 4, 256, 0, stream>>>(xh, cursor, bucket, seg,
                                                 (unsigned long long*)mask);
  gemm_kernel  <<<NBLK, 512, 0, stream>>>(xh, seg, Wp, bias, mask, out);
}

// Round 18
// 154.962 us; speedup vs baseline: 1.1204x; 1.0746x over previous
//
#include <hip/hip_runtime.h>
#include <hip/hip_fp16.h>
#include <math.h>

#define N_NODES 50000
#define F_DIM   128
#define E_EDGES 800000
#define NPB     32      // nodes per gemm block -> 1563 blocks (last block 16 rows)
#define NBLK    1563
#define CAP     64      // bucket capacity per node
#define APAD_H  136     // padded row stride in halves (272 B = 17 x 16B)
#define FILL_BLOCKS (E_EDGES / 256)            // 3125
#define PACK_BLOCKS ((N_NODES * F_DIM) / 1024) // 6250
#define WPACK_BLOCKS 64                        // 2*128*64 half2 words / 256

typedef _Float16 f16x8 __attribute__((ext_vector_type(8)));
typedef float    f32x4 __attribute__((ext_vector_type(4)));

// ---------------- JAX threefry (partitionable path, o0^o1) — verified r2 ----------------
__device__ __forceinline__ unsigned rotl32(unsigned x, int d) {
  return (x << d) | (x >> (32 - d));
}

__device__ __forceinline__ void tf2x32(unsigned k0, unsigned k1,
                                       unsigned c0, unsigned c1,
                                       unsigned &o0, unsigned &o1) {
  unsigned ks2 = k0 ^ k1 ^ 0x1BD11BDAu;
  unsigned x0 = c0 + k0, x1 = c1 + k1;
#define TF_R(a) { x0 += x1; x1 = rotl32(x1, a); x1 ^= x0; }
  TF_R(13) TF_R(15) TF_R(26) TF_R(6)   x0 += k1;  x1 += ks2 + 1u;
  TF_R(17) TF_R(29) TF_R(16) TF_R(24)  x0 += ks2; x1 += k0 + 2u;
  TF_R(13) TF_R(15) TF_R(26) TF_R(6)   x0 += k0;  x1 += k1 + 3u;
  TF_R(17) TF_R(29) TF_R(16) TF_R(24)  x0 += k1;  x1 += ks2 + 4u;
  TF_R(13) TF_R(15) TF_R(26) TF_R(6)   x0 += ks2; x1 += k0 + 5u;
#undef TF_R
  o0 = x0; o1 = x1;
}

__device__ __forceinline__ bool keep_elem(unsigned j) {
  unsigned o0, o1;
  tf2x32(0u, 42u, 0u, j, o0, o1);
  unsigned bits = o0 ^ o1;
  float uf = __uint_as_float((bits >> 9) | 0x3f800000u) - 1.0f;
  return uf < 0.7f;
}

// --- prep: bucket fill (u16) | fp16 pack of x | fp16 c-major pack of W ---
__global__ __launch_bounds__(256) void prep(const float* __restrict__ x,
                                            __half* __restrict__ xh,
                                            const int* __restrict__ src,
                                            const int* __restrict__ dst,
                                            const float* __restrict__ Wself,
                                            const float* __restrict__ Wneigh,
                                            float* __restrict__ Wp,
                                            int* __restrict__ cursor,
                                            unsigned short* __restrict__ bucket) {
  int b = blockIdx.x;
  if (b < FILL_BLOCKS) {
    int e = b * 256 + threadIdx.x;
    int d = dst[e];
    int pos = atomicAdd(&cursor[d], 1);
    if (pos < CAP) bucket[d * CAP + pos] = (unsigned short)src[e];
  } else if (b < FILL_BLOCKS + PACK_BLOCKS) {
    int i = (b - FILL_BLOCKS) * 256 + threadIdx.x;   // one float4 -> 8B half4
    float4 v = ((const float4*)x)[i];
    __half2 h01 = __floats2half2_rn(v.x, v.y);
    __half2 h23 = __floats2half2_rn(v.z, v.w);
    float2 o;
    o.x = __uint_as_float(*(const unsigned*)&h01);
    o.y = __uint_as_float(*(const unsigned*)&h23);
    ((float2*)xh)[i] = o;
  } else {
    // W pack, c-major k-pairs: Wp[h][c][k2] = half2(W[2k2][c], W[2k2+1][c])
    int idx = (b - FILL_BLOCKS - PACK_BLOCKS) * 256 + threadIdx.x;  // [0, 16384)
    int h = idx >> 13, rem = idx & 8191;
    int k2 = rem >> 7, c = rem & 127;
    const float* Ws = h ? Wneigh : Wself;
    __half2 hh = __floats2half2_rn(Ws[(k2 * 2) * 128 + c], Ws[(k2 * 2 + 1) * 128 + c]);
    Wp[h * 8192 + c * 64 + k2] = __builtin_bit_cast(float, hh);
  }
}

// ---- gather: one 64-lane wave per node; zero LDS; 8 loads in flight ----
// Also generates the dropout bitmask (threefry+ballot) — hides under vmcnt stalls.
__global__ __launch_bounds__(256) void gather_kernel(const __half* __restrict__ xh,
                                                     const int* __restrict__ cursor,
                                                     const unsigned short* __restrict__ bucket,
                                                     __half* __restrict__ seg,
                                                     unsigned long long* __restrict__ mask64) {
  const int w = threadIdx.x >> 6, li = threadIdx.x & 63;
  const int n = blockIdx.x * 4 + w;          // 12500 * 4 = 50000 exactly
  int deg = cursor[n]; deg = deg < CAP ? deg : CAP;
  float sx = 0.f, sy = 0.f;
  const unsigned* xr = (const unsigned*)xh;  // dword = half2; row stride 64
  const unsigned short* ep = bucket + (size_t)n * CAP;  // wave-uniform
  for (int j0 = 0; j0 < deg; j0 += 8) {
    int idx[8];
#pragma unroll
    for (int k = 0; k < 8; ++k) {
      int j = j0 + k;
      idx[k] = ep[j < deg ? j : deg - 1];    // clamped -> always a valid slot
    }
    unsigned u[8];
#pragma unroll
    for (int k = 0; k < 8; ++k)
      u[k] = xr[(size_t)idx[k] * 64 + li];   // 8 independent coalesced dwords
#pragma unroll
    for (int k = 0; k < 8; ++k)
      if (j0 + k < deg) {
        float2 f = __half22float2(__builtin_bit_cast(__half2, u[k]));
        sx += f.x; sy += f.y;
      }
  }
  // dropout mask: block covers elements [blockIdx*1024, +1024) = 16 u64 words
  {
    unsigned j0 = (unsigned)blockIdx.x * 1024u + (unsigned)w * 256u;
#pragma unroll
    for (int r = 0; r < 4; ++r) {
      unsigned j = j0 + (unsigned)r * 64u + (unsigned)li;
      unsigned long long b = __ballot(keep_elem(j));
      if (li == 0) mask64[(size_t)blockIdx.x * 16 + w * 4 + r] = b;
    }
  }
  float iv = 1.0f / (float)(deg > 1 ? deg : 1);
  __half2 r = __floats2half2_rn(sx * iv, sy * iv);
  ((unsigned*)seg)[(size_t)n * 64 + li] = __builtin_bit_cast(unsigned, r);
}

// ---- gemm: MFMA 16x16x32_f16. 512 thr = 8 waves; wave (h, rb, cbg) owns 4 16x16 tiles ----
// A: row=lane&15, k=(lane>>4)*8+j (8 contiguous halves).  B: col=lane&15, k likewise.
// C/D: col=lane&15, row=(lane>>4)*4+reg  [verified m89].
__global__ __launch_bounds__(512) void gemm_kernel(
    const __half* __restrict__ xh, const __half* __restrict__ seg,
    const float* __restrict__ Wp, const float* __restrict__ bias,
    const unsigned* __restrict__ mask, float* __restrict__ out) {
  __shared__ __align__(16) __half Ah[2][NPB][APAD_H];   // 17.4 KB
  __shared__ float wsum[2][2][2][16];                   // [rb][h][cbg][row16]

  const int t = threadIdx.x;
  const int row0 = blockIdx.x * NPB;

  // ---- stage self + mean rows (1024 x 16B granules, 2/thread, coalesced) ----
#pragma unroll
  for (int k = 0; k < 2; ++k) {
    int q = k * 512 + t;
    int arr = q >> 9, rem = q & 511;
    int row = rem >> 4, f8 = rem & 15;
    int grow = row0 + row;
    if (grow > N_NODES - 1) grow = N_NODES - 1;
    const __half* sp = arr ? seg : xh;
    *(float4*)&Ah[arr][row][f8 * 8] = ((const float4*)sp)[(size_t)grow * 16 + f8];
  }
  __syncthreads();

  const int wid = t >> 6, lane = t & 63;
  const int h = wid >> 2, rb = wid & 1, cbg = (wid >> 1) & 1;
  const int c15 = lane & 15, hi = lane >> 4;

  // ---- A fragments: 4 k-chunks of this wave's 16-row block ----
  f16x8 afrag[4];
#pragma unroll
  for (int kc = 0; kc < 4; ++kc)
    afrag[kc] = *(const f16x8*)&Ah[h][rb * 16 + c15][kc * 32 + hi * 8];

  // ---- MFMA: 4 col-tiles x 4 K-chunks ----
  const float4* Wb4 = (const float4*)Wp + h * 2048;   // [c][16 float4 of k-pairs]
  f32x4 acc[4];
#pragma unroll
  for (int ct = 0; ct < 4; ++ct) acc[ct] = (f32x4){0.f, 0.f, 0.f, 0.f};

#pragma unroll
  for (int ct = 0; ct < 4; ++ct) {
    int col_h = cbg * 64 + ct * 16 + c15;
#pragma unroll
    for (int kc = 0; kc < 4; ++kc) {
      float4 br = Wb4[col_h * 16 + kc * 4 + hi];
      acc[ct] = __builtin_amdgcn_mfma_f32_16x16x32_f16(
          afrag[kc], __builtin_bit_cast(f16x8, br), acc[ct], 0, 0, 0);
    }
  }

  // ---- epilogue: +bias, ELU, dropout (bitmask), partial sum-of-squares ----
  float ssr[4] = {0.f, 0.f, 0.f, 0.f};
#pragma unroll
  for (int ct = 0; ct < 4; ++ct) {
    int col_h = cbg * 64 + ct * 16 + c15;
    float b = bias[h * 128 + col_h];
#pragma unroll
    for (int reg = 0; reg < 4; ++reg) {
      unsigned n = row0 + rb * 16 + hi * 4 + reg;
      float val = acc[ct][reg] + b;
      val = (val > 0.0f) ? val : expm1f(val);
      unsigned mw = (n < N_NODES)
                        ? mask[n * 8u + (unsigned)h * 4u + (unsigned)(cbg * 2 + (ct >> 1))]
                        : 0u;
      val = ((mw >> ((ct & 1) * 16 + c15)) & 1u) ? val * (1.0f / 0.7f) : 0.0f;
      acc[ct][reg] = val;
      ssr[reg] = fmaf(val, val, ssr[reg]);
    }
  }
  // reduce over the 16 col-lanes (width 16 stays within the hi group)
#pragma unroll
  for (int d = 1; d < 16; d <<= 1)
#pragma unroll
    for (int reg = 0; reg < 4; ++reg) ssr[reg] += __shfl_xor(ssr[reg], d, 16);
  if (c15 == 0) {
#pragma unroll
    for (int reg = 0; reg < 4; ++reg) wsum[rb][h][cbg][hi * 4 + reg] = ssr[reg];
  }
  __syncthreads();

  // ---- l2norm + store ----
#pragma unroll
  for (int reg = 0; reg < 4; ++reg) {
    int r16 = hi * 4 + reg;
    float tot = wsum[rb][0][0][r16] + wsum[rb][0][1][r16] +
                wsum[rb][1][0][r16] + wsum[rb][1][1][r16];
    float sc = rsqrtf(fmaxf(tot, 1e-12f));
    size_t n = (size_t)(row0 + rb * 16 + r16);
    if (n < N_NODES) {
#pragma unroll
      for (int ct = 0; ct < 4; ++ct)
        out[n * 256 + h * 128 + cbg * 64 + ct * 16 + c15] = acc[ct][reg] * sc;
    }
  }
}

extern "C" void kernel_launch(void* const* d_in, const int* in_sizes, int n_in,
                              void* d_out, int out_size, void* d_ws, size_t ws_size,
                              hipStream_t stream) {
  const float* x      = (const float*)d_in[0];
  const float* Wself  = (const float*)d_in[1];
  const float* Wneigh = (const float*)d_in[2];
  const float* bias   = (const float*)d_in[3];
  const int*   src    = (const int*)d_in[4];   // jnp.int64 degrades to int32 (x64 off)
  const int*   dst    = (const int*)d_in[5];
  float* out = (float*)d_out;

  char* p = (char*)d_ws;
  int*            cursor = (int*)p;                       // 200,000 B (pad 200,704)
  unsigned short* bucket = (unsigned short*)(p + 200704); // 6,400,000 B
  __half*         seg    = (__half*)(p + 6600704);        // 12,800,000 B
  __half*         xh     = (__half*)(p + 19400704);       // 12,800,000 B
  unsigned*       mask   = (unsigned*)(p + 32200704);     // 1,600,000 B (8B-aligned)
  float*          Wp     = (float*)(p + 33800704);        // 65,536 B (end ~33.9 MB)

  hipMemsetAsync(cursor, 0, 200000, stream);
  prep<<<FILL_BLOCKS + PACK_BLOCKS + WPACK_BLOCKS, 256, 0, stream>>>(
      x, xh, src, dst, Wself, Wneigh, Wp, cursor, bucket);
  gather_kernel<<<N_NODES / 4, 256, 0, stream>>>(xh, cursor, bucket, seg,
                                                 (unsigned long long*)mask);
  gemm_kernel  <<<NBLK, 512, 0, stream>>>(xh, seg, Wp, bias, mask, out);
}

// Round 19
// 129.404 us; speedup vs baseline: 1.3417x; 1.1975x over previous
//
#include <hip/hip_runtime.h>
#include <hip/hip_fp16.h>
#include <math.h>

#define N_NODES 50000
#define F_DIM   128
#define E_EDGES 800000
#define NPB     32      // nodes per gemm block -> 1563 blocks (last block 16 rows)
#define NBLK    1563
#define CAP     64      // bucket capacity per node
#define APAD_H  136     // padded row stride in halves (272 B = 17 x 16B)
#define NMASKW  400000  // 12.8M elements / 32 bits
#define FILL_BLOCKS (E_EDGES / 256)            // 3125
#define PACK_BLOCKS ((N_NODES * F_DIM) / 1024) // 6250
#define WPACK_BLOCKS 64                        // 2*128*64 half2 words / 256

typedef _Float16 f16x8 __attribute__((ext_vector_type(8)));
typedef float    f32x4 __attribute__((ext_vector_type(4)));

// ---------------- JAX threefry (partitionable path, o0^o1) — verified r2 ----------------
__device__ __forceinline__ unsigned rotl32(unsigned x, int d) {
  return (x << d) | (x >> (32 - d));
}

__device__ __forceinline__ void tf2x32(unsigned k0, unsigned k1,
                                       unsigned c0, unsigned c1,
                                       unsigned &o0, unsigned &o1) {
  unsigned ks2 = k0 ^ k1 ^ 0x1BD11BDAu;
  unsigned x0 = c0 + k0, x1 = c1 + k1;
#define TF_R(a) { x0 += x1; x1 = rotl32(x1, a); x1 ^= x0; }
  TF_R(13) TF_R(15) TF_R(26) TF_R(6)   x0 += k1;  x1 += ks2 + 1u;
  TF_R(17) TF_R(29) TF_R(16) TF_R(24)  x0 += ks2; x1 += k0 + 2u;
  TF_R(13) TF_R(15) TF_R(26) TF_R(6)   x0 += k0;  x1 += k1 + 3u;
  TF_R(17) TF_R(29) TF_R(16) TF_R(24)  x0 += k1;  x1 += ks2 + 4u;
  TF_R(13) TF_R(15) TF_R(26) TF_R(6)   x0 += ks2; x1 += k0 + 5u;
#undef TF_R
  o0 = x0; o1 = x1;
}

__device__ __forceinline__ bool keep_elem(unsigned j) {
  unsigned o0, o1;
  tf2x32(0u, 42u, 0u, j, o0, o1);
  unsigned bits = o0 ^ o1;
  float uf = __uint_as_float((bits >> 9) | 0x3f800000u) - 1.0f;
  return uf < 0.7f;
}

// --- prep: bucket fill (u16) + dropout mask | fp16 pack of x | c-major W pack ---
__global__ __launch_bounds__(256) void prep(const float* __restrict__ x,
                                            __half* __restrict__ xh,
                                            const int* __restrict__ src,
                                            const int* __restrict__ dst,
                                            const float* __restrict__ Wself,
                                            const float* __restrict__ Wneigh,
                                            float* __restrict__ Wp,
                                            int* __restrict__ cursor,
                                            unsigned short* __restrict__ bucket,
                                            unsigned* __restrict__ mask) {
  int b = blockIdx.x;
  if (b < FILL_BLOCKS) {
    int e = b * 256 + threadIdx.x;
    int d = dst[e];
    int pos = atomicAdd(&cursor[d], 1);
    if (pos < CAP) bucket[d * CAP + pos] = (unsigned short)src[e];
    if (e < NMASKW) {                       // threefry hides under memory stalls
      unsigned base = (unsigned)e * 32u;
      unsigned w = 0;
#pragma unroll 4
      for (int bb = 0; bb < 32; ++bb) w |= (keep_elem(base + bb) ? 1u : 0u) << bb;
      mask[e] = w;
    }
  } else if (b < FILL_BLOCKS + PACK_BLOCKS) {
    int i = (b - FILL_BLOCKS) * 256 + threadIdx.x;   // one float4 -> 8B half4
    float4 v = ((const float4*)x)[i];
    __half2 h01 = __floats2half2_rn(v.x, v.y);
    __half2 h23 = __floats2half2_rn(v.z, v.w);
    float2 o;
    o.x = __uint_as_float(*(const unsigned*)&h01);
    o.y = __uint_as_float(*(const unsigned*)&h23);
    ((float2*)xh)[i] = o;
  } else {
    // W pack, c-major k-pairs: Wp[h][c][k2] = half2(W[2k2][c], W[2k2+1][c])
    int idx = (b - FILL_BLOCKS - PACK_BLOCKS) * 256 + threadIdx.x;  // [0, 16384)
    int h = idx >> 13, rem = idx & 8191;
    int k2 = rem >> 7, c = rem & 127;
    const float* Ws = h ? Wneigh : Wself;
    __half2 hh = __floats2half2_rn(Ws[(k2 * 2) * 128 + c], Ws[(k2 * 2 + 1) * 128 + c]);
    Wp[h * 8192 + c * 64 + k2] = __builtin_bit_cast(float, hh);
  }
}

// ---- gather: one 64-lane wave per node; zero LDS; 8 loads in flight ----
// Accumulates in packed fp16 (__hadd2): 1 VALU inst per edge-dword.
__global__ __launch_bounds__(256) void gather_kernel(const __half* __restrict__ xh,
                                                     const int* __restrict__ cursor,
                                                     const unsigned short* __restrict__ bucket,
                                                     __half* __restrict__ seg) {
  const int w = threadIdx.x >> 6, li = threadIdx.x & 63;
  const int n = blockIdx.x * 4 + w;          // 12500 * 4 = 50000 exactly
  int deg = cursor[n]; deg = deg < CAP ? deg : CAP;
  __half2 sum = __floats2half2_rn(0.f, 0.f);
  const unsigned* xr = (const unsigned*)xh;  // dword = half2; row stride 64
  const unsigned short* ep = bucket + (size_t)n * CAP;  // wave-uniform
  for (int j0 = 0; j0 < deg; j0 += 8) {
    int idx[8];
#pragma unroll
    for (int k = 0; k < 8; ++k) {
      int j = j0 + k;
      idx[k] = ep[j < deg ? j : deg - 1];    // clamped -> always a valid slot
    }
    unsigned u[8];
#pragma unroll
    for (int k = 0; k < 8; ++k)
      u[k] = xr[(size_t)idx[k] * 64 + li];   // 8 independent coalesced dwords
#pragma unroll
    for (int k = 0; k < 8; ++k)
      if (j0 + k < deg)
        sum = __hadd2(sum, __builtin_bit_cast(__half2, u[k]));
  }
  float iv = 1.0f / (float)(deg > 1 ? deg : 1);
  float2 f = __half22float2(sum);
  __half2 r = __floats2half2_rn(f.x * iv, f.y * iv);
  ((unsigned*)seg)[(size_t)n * 64 + li] = __builtin_bit_cast(unsigned, r);
}

// ---- gemm: MFMA 16x16x32_f16. 512 thr = 8 waves; wave (h, rb, cbg) owns 4 16x16 tiles ----
// A: row=lane&15, k=(lane>>4)*8+j.  B: col=lane&15, k likewise.
// C/D: col=lane&15, row=(lane>>4)*4+reg  [verified m89 + r18 pass].
__global__ __launch_bounds__(512) void gemm_kernel(
    const __half* __restrict__ xh, const __half* __restrict__ seg,
    const float* __restrict__ Wp, const float* __restrict__ bias,
    const unsigned* __restrict__ mask, float* __restrict__ out) {
  __shared__ __align__(16) __half Ah[2][NPB][APAD_H];   // 17.4 KB
  __shared__ float wsum[2][2][2][16];                   // [rb][h][cbg][row16]

  const int t = threadIdx.x;
  const int row0 = blockIdx.x * NPB;

  // ---- stage self + mean rows (1024 x 16B granules, 2/thread, coalesced) ----
#pragma unroll
  for (int k = 0; k < 2; ++k) {
    int q = k * 512 + t;
    int arr = q >> 9, rem = q & 511;
    int row = rem >> 4, f8 = rem & 15;
    int grow = row0 + row;
    if (grow > N_NODES - 1) grow = N_NODES - 1;
    const __half* sp = arr ? seg : xh;
    *(float4*)&Ah[arr][row][f8 * 8] = ((const float4*)sp)[(size_t)grow * 16 + f8];
  }
  __syncthreads();

  const int wid = t >> 6, lane = t & 63;
  const int h = wid >> 2, rb = wid & 1, cbg = (wid >> 1) & 1;
  const int c15 = lane & 15, hi = lane >> 4;

  // ---- A fragments: 4 k-chunks of this wave's 16-row block ----
  f16x8 afrag[4];
#pragma unroll
  for (int kc = 0; kc < 4; ++kc)
    afrag[kc] = *(const f16x8*)&Ah[h][rb * 16 + c15][kc * 32 + hi * 8];

  // ---- MFMA: 4 col-tiles x 4 K-chunks ----
  const float4* Wb4 = (const float4*)Wp + h * 2048;   // [c][16 float4 of k-pairs]
  f32x4 acc[4];
#pragma unroll
  for (int ct = 0; ct < 4; ++ct) acc[ct] = (f32x4){0.f, 0.f, 0.f, 0.f};

#pragma unroll
  for (int ct = 0; ct < 4; ++ct) {
    int col_h = cbg * 64 + ct * 16 + c15;
#pragma unroll
    for (int kc = 0; kc < 4; ++kc) {
      float4 br = Wb4[col_h * 16 + kc * 4 + hi];
      acc[ct] = __builtin_amdgcn_mfma_f32_16x16x32_f16(
          afrag[kc], __builtin_bit_cast(f16x8, br), acc[ct], 0, 0, 0);
    }
  }

  // ---- epilogue: +bias, ELU, dropout (bitmask), partial sum-of-squares ----
  float ssr[4] = {0.f, 0.f, 0.f, 0.f};
#pragma unroll
  for (int ct = 0; ct < 4; ++ct) {
    int col_h = cbg * 64 + ct * 16 + c15;
    float b = bias[h * 128 + col_h];
#pragma unroll
    for (int reg = 0; reg < 4; ++reg) {
      unsigned n = row0 + rb * 16 + hi * 4 + reg;
      float val = acc[ct][reg] + b;
      val = (val > 0.0f) ? val : expm1f(val);
      unsigned mw = (n < N_NODES)
                        ? mask[n * 8u + (unsigned)h * 4u + (unsigned)(cbg * 2 + (ct >> 1))]
                        : 0u;
      val = ((mw >> ((ct & 1) * 16 + c15)) & 1u) ? val * (1.0f / 0.7f) : 0.0f;
      acc[ct][reg] = val;
      ssr[reg] = fmaf(val, val, ssr[reg]);
    }
  }
  // reduce over the 16 col-lanes (width 16 stays within the hi group)
#pragma unroll
  for (int d = 1; d < 16; d <<= 1)
#pragma unroll
    for (int reg = 0; reg < 4; ++reg) ssr[reg] += __shfl_xor(ssr[reg], d, 16);
  if (c15 == 0) {
#pragma unroll
    for (int reg = 0; reg < 4; ++reg) wsum[rb][h][cbg][hi * 4 + reg] = ssr[reg];
  }
  __syncthreads();

  // ---- l2norm + store ----
#pragma unroll
  for (int reg = 0; reg < 4; ++reg) {
    int r16 = hi * 4 + reg;
    float tot = wsum[rb][0][0][r16] + wsum[rb][0][1][r16] +
                wsum[rb][1][0][r16] + wsum[rb][1][1][r16];
    float sc = rsqrtf(fmaxf(tot, 1e-12f));
    size_t n = (size_t)(row0 + rb * 16 + r16);
    if (n < N_NODES) {
#pragma unroll
      for (int ct = 0; ct < 4; ++ct)
        out[n * 256 + h * 128 + cbg * 64 + ct * 16 + c15] = acc[ct][reg] * sc;
    }
  }
}

extern "C" void kernel_launch(void* const* d_in, const int* in_sizes, int n_in,
                              void* d_out, int out_size, void* d_ws, size_t ws_size,
                              hipStream_t stream) {
  const float* x      = (const float*)d_in[0];
  const float* Wself  = (const float*)d_in[1];
  const float* Wneigh = (const float*)d_in[2];
  const float* bias   = (const float*)d_in[3];
  const int*   src    = (const int*)d_in[4];   // jnp.int64 degrades to int32 (x64 off)
  const int*   dst    = (const int*)d_in[5];
  float* out = (float*)d_out;

  char* p = (char*)d_ws;
  int*            cursor = (int*)p;                       // 200,000 B (pad 200,704)
  unsigned short* bucket = (unsigned short*)(p + 200704); // 6,400,000 B
  __half*         seg    = (__half*)(p + 6600704);        // 12,800,000 B
  __half*         xh     = (__half*)(p + 19400704);       // 12,800,000 B
  unsigned*       mask   = (unsigned*)(p + 32200704);     // 1,600,000 B
  float*          Wp     = (float*)(p + 33800704);        // 65,536 B (end ~33.9 MB)

  hipMemsetAsync(cursor, 0, 200000, stream);
  prep<<<FILL_BLOCKS + PACK_BLOCKS + WPACK_BLOCKS, 256, 0, stream>>>(
      x, xh, src, dst, Wself, Wneigh, Wp, cursor, bucket, mask);
  gather_kernel<<<N_NODES / 4, 256, 0, stream>>>(xh, cursor, bucket, seg);
  gemm_kernel  <<<NBLK, 512, 0, stream>>>(xh, seg, Wp, bias, mask, out);
}